// Round 2
// baseline (2400.809 us; speedup 1.0000x reference)
//
#include <hip/hip_runtime.h>

// Needleman-Wunsch soft-DP (logsumexp-smoothed), linear-domain wavefront.
// V[i,j] = theta[i-1,j-1] + LSE(A+V[i-1,j], V[i-1,j-1], A+V[i,j-1])
// W-domain with BLOCK-UNIFORM power-of-2 scale oacc (identical in all threads):
//   stored = exp(V) * 2^-oacc;  W[i,j] = e^th * (e^A*(up+left) + diag)
// Boundary V=-1e10 -> W=0 exactly. Output = log(W_corner) + oacc*ln2.

constexpr int NDP = 2048;
constexpr int MDP = 2048;
constexpr int NTH = 512;            // 8 waves, 1 workgroup
constexpr int RPT = 4;              // rows per thread; NTH*RPT == NDP
constexpr int NWAVE = NTH / 64;
constexpr int DTOT = NDP + MDP;     // last anti-diagonal (4096)
constexpr float LOG2E = 1.44269504088896340736f;
constexpr float LN2   = 0.69314718055994530942f;

// Pre-pass: theta -> diagonal-major thD[(d-2)*NDP + (i-1)] = theta[i-1, d-i-1]
__global__ void diagify(const float* __restrict__ theta, float* __restrict__ thD)
{
  long long idx = (long long)blockIdx.x * blockDim.x + threadIdx.x;
  const long long total = (long long)(DTOT - 1) * NDP;   // 4095 * 2048
  if (idx >= total) return;
  int i0 = (int)(idx & (NDP - 1));    // i-1
  int dd = (int)(idx >> 11);          // d-2
  int j  = dd - i0 + 1;               // j = d - i
  float v = 0.f;
  if ((unsigned)(j - 1) < (unsigned)MDP) v = theta[(size_t)i0 * MDP + (j - 1)];
  thD[idx] = v;
}

template<bool DIAG>
__global__ __launch_bounds__(NTH)
void nw_main(const float* __restrict__ th,   // DIAG ? thD : theta (row-major)
             const float* __restrict__ Aptr,
             float* __restrict__ out)
{
  const int tid  = threadIdx.x;
  const int lane = tid & 63;
  const int wid  = tid >> 6;

  __shared__ float handW[2][NTH];     // cross-thread hand-off, double-buffered
  __shared__ float wmax[2][NWAVE];    // per-wave maxima for uniform rescale

  const float A  = Aptr[0];
  const float eA = __builtin_exp2f(A * LOG2E);
  const int i_base = tid * RPT + 1;   // thread owns DP rows i_base .. i_base+3

  // own rows at diag d-1 (W1x) and d-2 (W2x), all in the global scale
  float W10=0.f, W11=0.f, W12=0.f, W13=0.f;
  float W20=0.f, W21=0.f, W22=0.f, W23=0.f;
  float nb1 = 0.f;                          // row i_base-1 at diag d-1
  float nb2 = (tid == 0) ? 1.f : 0.f;       // row i_base-1 at diag d-2; V[0,0]=0 -> W=1
  int oacc = 0;                             // block-uniform scale (identical everywhere)

  const float* thb = DIAG ? th : (th + (size_t)(i_base - 1) * MDP);

  auto loadTh = [&](int d) -> float4 {
    if constexpr (DIAG) {
      int dd = min(d, DTOT) - 2;            // clamp prefetch past the end
      return *reinterpret_cast<const float4*>(th + (size_t)dd * NDP + tid * RPT);
    } else {
      float4 r;
      int c0 = min(max(d - i_base - 1, 0), MDP - 1);
      int c1 = min(max(d - i_base - 2, 0), MDP - 1);
      int c2 = min(max(d - i_base - 3, 0), MDP - 1);
      int c3 = min(max(d - i_base - 4, 0), MDP - 1);
      r.x = thb[c0];
      r.y = thb[(size_t)MDP + c1];
      r.z = thb[(size_t)2 * MDP + c2];
      r.w = thb[(size_t)3 * MDP + c3];
      return r;
    }
  };

  float4 thA = loadTh(2);    // theta for diag d
  float4 thB = loadTh(3);    // theta for diag d+1

  for (int d = 2; d <= DTOT; ++d) {
    float4 thC = loadTh(d + 2);   // prefetch 2 ahead

    // W[i,j] = e^th * (eA*(up+left) + diag); row r=0 uses neighbor hand-offs
    float n0 = __builtin_exp2f(thA.x * LOG2E) * (eA * (nb1 + W10) + nb2);
    float n1 = __builtin_exp2f(thA.y * LOG2E) * (eA * (W10 + W11) + W20);
    float n2 = __builtin_exp2f(thA.z * LOG2E) * (eA * (W11 + W12) + W21);
    float n3 = __builtin_exp2f(thA.w * LOG2E) * (eA * (W12 + W13) + W22);

    // shift diag buffers; mask invalid cells (j out of [1,M]) to exact 0
    W20 = W10; W21 = W11; W22 = W12; W23 = W13;
    int cb = d - i_base - 1;                 // column-1 of row r=0 on diag d
    W10 = ((unsigned)(cb)     < (unsigned)MDP) ? n0 : 0.f;
    W11 = ((unsigned)(cb - 1) < (unsigned)MDP) ? n1 : 0.f;
    W12 = ((unsigned)(cb - 2) < (unsigned)MDP) ? n2 : 0.f;
    W13 = ((unsigned)(cb - 3) < (unsigned)MDP) ? n3 : 0.f;

    const int buf  = d & 1;
    const bool rs  = ((d & 1) == 0);         // rescale every 2 diagonals
    const int wbuf = (d >> 1) & 1;

    if (rs) {
      float m = fmaxf(fmaxf(W10, W11), fmaxf(W12, W13));
      m = fmaxf(m, __shfl_xor(m, 1, 64));
      m = fmaxf(m, __shfl_xor(m, 2, 64));
      m = fmaxf(m, __shfl_xor(m, 4, 64));
      m = fmaxf(m, __shfl_xor(m, 8, 64));
      m = fmaxf(m, __shfl_xor(m, 16, 64));
      m = fmaxf(m, __shfl_xor(m, 32, 64));
      if (lane == 0) wmax[wbuf][wid] = m;
    }
    handW[buf][tid] = W13;                   // pass last row to thread tid+1
    __syncthreads();

    nb2 = nb1;                               // becomes diag d-1 for step d+1
    nb1 = (tid == 0) ? 0.f : handW[buf][tid - 1];  // row i_base-1 at diag d

    if (rs) {
      // identical block max -> identical e in every thread (no conversions)
      float bm = wmax[wbuf][0];
#pragma unroll
      for (int w = 1; w < NWAVE; ++w) bm = fmaxf(bm, wmax[wbuf][w]);
      int e = 0;
      if (bm > 0.f) e = (int)((__float_as_uint(bm) >> 23) & 0xFFu) - 126;
      if (e != 0) {
        W10 = ldexpf(W10, -e); W11 = ldexpf(W11, -e);
        W12 = ldexpf(W12, -e); W13 = ldexpf(W13, -e);
        W20 = ldexpf(W20, -e); W21 = ldexpf(W21, -e);
        W22 = ldexpf(W22, -e); W23 = ldexpf(W23, -e);
        nb1 = ldexpf(nb1, -e); nb2 = ldexpf(nb2, -e);
        oacc += e;
      }
    }

    thA = thB; thB = thC;                    // rotate theta ring
  }

  // V[N,M] sits in thread NTH-1, row RPT-1; last rescale put it in [0.5,1)
  if (tid == NTH - 1) out[0] = logf(W13) + (float)oacc * LN2;
}

extern "C" void kernel_launch(void* const* d_in, const int* in_sizes, int n_in,
                              void* d_out, int out_size, void* d_ws, size_t ws_size,
                              hipStream_t stream)
{
  const float* theta = (const float*)d_in[0];
  const float* A     = (const float*)d_in[1];
  float* out = (float*)d_out;

  const size_t need = (size_t)(DTOT - 1) * NDP * sizeof(float);  // 33.5 MB
  if (ws_size >= need) {
    float* thD = (float*)d_ws;
    const long long total = (long long)(DTOT - 1) * NDP;
    const int blocks = (int)((total + 255) / 256);
    hipLaunchKernelGGL(diagify, dim3(blocks), dim3(256), 0, stream, theta, thD);
    hipLaunchKernelGGL((nw_main<true>), dim3(1), dim3(NTH), 0, stream, thD, A, out);
  } else {
    hipLaunchKernelGGL((nw_main<false>), dim3(1), dim3(NTH), 0, stream, theta, A, out);
  }
}

// Round 4
// 1152.031 us; speedup vs baseline: 2.0840x; 2.0840x over previous
//
#include <hip/hip_runtime.h>

// Needleman-Wunsch soft-DP (logsumexp-smoothed), linear-domain, pipelined
// across 16 workgroups (1 wave each, 2 rows/thread, 128 rows/WG).
// W = exp(V - oacc*ln2) per-WG scale; cross-WG boundary passed in ABSOLUTE
// log2 domain (scale-free) via global ring + release/acquire flags.

constexpr int NDP = 2048;
constexpr int MDP = 2048;
constexpr int G    = 16;            // workgroups
constexpr int RPW  = 128;           // rows per WG
constexpr int BATCH = 32;           // diagonals per sync batch
constexpr int NB    = 68;           // batches: 68*32 = 2176 >= 128+2048-1 steps
constexpr int DTOT  = NDP + MDP;    // 4096
constexpr int DVB   = 4160;         // per-WG boundary buffer stride (floats)
constexpr float LOG2E = 1.44269504088896340736f;
constexpr float LN2   = 0.69314718055994530942f;

__device__ __forceinline__ float neginf() { return __int_as_float(0xff800000); }

__global__ __launch_bounds__(64)
void nw_pipe(const float* __restrict__ theta, const float* __restrict__ Aptr,
             float* __restrict__ out, float* __restrict__ vbBase,
             int* __restrict__ flags)
{
  const int wg   = blockIdx.x;
  const int lane = threadIdx.x;

  const float A  = Aptr[0];
  const float eA = __builtin_exp2f(A * LOG2E);

  const int S   = wg * RPW + 2;              // first diagonal with a cell in band
  const int rA0 = wg * RPW + 2 * lane;       // 0-indexed row (i-1) of row "A"
  const int rB0 = rA0 + 1;
  const float* thA_p = theta + (size_t)rA0 * MDP;
  const float* thB_p = theta + (size_t)rB0 * MDP;
  const int endA = rA0 + 1 + MDP;            // last valid diag for row A
  const int endB = endA + 1;

  float* vbMine = vbBase + (size_t)wg * DVB;
  const float* vbProd = vbBase + (size_t)(wg - 1) * DVB;
  int* flagProd = flags + (wg - 1) * 16;
  int* flagMine = flags + wg * 16;
  const int eMaxProd = (wg > 0) ? (wg * RPW + MDP) : -1;

  float WA1 = 0.f, WA2 = 0.f, WB1 = 0.f, WB2 = 0.f;
  float bu = 0.f, bd = (wg == 0) ? 1.f : 0.f;   // boundary inputs (our scale); bd=1 seeds V[0,0]
  float oaccF = 0.f;
  bool  init  = (wg == 0);
  float corner = 0.f;
  float vbReg = neginf();

  // theta register buffers: [group u][step k], rows A and B (all indices static)
  float tba[4][8], tbb[4][8];
#pragma unroll
  for (int u = 0; u < 4; ++u)
#pragma unroll
    for (int k = 0; k < 8; ++k) {
      int d  = S + 8 * u + k;
      int cA = min(max(d - (rA0 + 1) - 1, 0), MDP - 1);
      int cB = min(max(d - (rB0 + 1) - 1, 0), MDP - 1);
      tba[u][k] = thA_p[cA];
      tbb[u][k] = thB_p[cB];
    }

  // batch-0 poll + boundary prefetch
  if (wg > 0) {
    const int E0 = S - 1;
    const int need = min(E0 + 31, eMaxProd);
    while (__hip_atomic_load(flagProd, __ATOMIC_ACQUIRE, __HIP_MEMORY_SCOPE_AGENT) < need)
      __builtin_amdgcn_s_sleep(2);
    int e = E0 + (lane & 31);
    vbReg = (e <= eMaxProd) ? vbProd[e] : neginf();
    float m = vbReg;
#pragma unroll
    for (int sh = 1; sh < 64; sh <<= 1) m = fmaxf(m, __shfl_xor(m, sh, 64));
    if (m > -1e30f) { oaccF = m; init = true; }
    bu = __builtin_exp2f(fminf(__shfl(vbReg, 0, 64) - oaccF, 120.f));
  }

  for (int b = 0; b < NB; ++b) {
    const int dBase = S + BATCH * b;
#pragma unroll
    for (int u = 0; u < 4; ++u) {
#pragma unroll
      for (int k = 0; k < 8; ++k) {
        const int d = dBase + 8 * u + k;
        float upA = __shfl_up(WB1, 1, 64);   // row above A, diag d-1
        float dgA = __shfl_up(WB2, 1, 64);   // row above A, diag d-2
        if (lane == 0) { upA = bu; dgA = bd; }
        const float tA = __builtin_exp2f(tba[u][k] * LOG2E);
        const float tB = __builtin_exp2f(tbb[u][k] * LOG2E);
        float nA = tA * (eA * (upA + WA1) + dgA);
        float nB = tB * (eA * (WA1 + WB1) + WA2);
        nA = (d <= endA) ? nA : 0.f;         // mask past row end (start is auto-zero)
        nB = (d <= endB) ? nB : 0.f;
        WA2 = WA1; WA1 = nA; WB2 = WB1; WB1 = nB;
        if (lane == 63) {                    // publish band-boundary row (absolute log2)
          float vlog = __builtin_log2f(WB1) + oaccF;
          vbMine[d] = vlog;
          if (d == DTOT) corner = vlog;
        }
        bd = bu;                             // pipeline boundary inputs
        if (!(u == 3 && k == 7)) {
          float v = __shfl(vbReg, 8 * u + k + 1, 64);  // static lane index
          bu = __builtin_exp2f(fminf(v - oaccF, 120.f));
        }
      }
      // uniform rescale every 8 steps (exact power-of-2; incl. boundary inputs)
      {
        float m = fmaxf(fmaxf(WA1, WB1), fmaxf(WA2, WB2));
        m = fmaxf(m, fmaxf(bu, bd));
#pragma unroll
        for (int sh = 1; sh < 64; sh <<= 1) m = fmaxf(m, __shfl_xor(m, sh, 64));
        int e = 0;
        if (m > 0.f) e = (int)((__float_as_uint(m) >> 23) & 0xFFu) - 126;
        if (e != 0) {
          WA1 = ldexpf(WA1, -e); WA2 = ldexpf(WA2, -e);
          WB1 = ldexpf(WB1, -e); WB2 = ldexpf(WB2, -e);
          bu  = ldexpf(bu,  -e); bd  = ldexpf(bd,  -e);
          oaccF += (float)e;
        }
      }
      // theta prefetch for next batch, same group (32-step distance)
      if (b + 1 < NB) {
#pragma unroll
        for (int k = 0; k < 8; ++k) {
          int d  = dBase + BATCH + 8 * u + k;
          int cA = min(max(d - (rA0 + 1) - 1, 0), MDP - 1);
          int cB = min(max(d - (rB0 + 1) - 1, 0), MDP - 1);
          tba[u][k] = thA_p[cA];
          tbb[u][k] = thB_p[cB];
        }
      }
    }
    // release boundary batch to consumer
    if (wg < G - 1 && lane == 63)
      __hip_atomic_store(flagMine, dBase + BATCH - 1, __ATOMIC_RELEASE, __HIP_MEMORY_SCOPE_AGENT);
    // acquire next boundary batch from producer
    if (b + 1 < NB && wg > 0) {
      const int E0 = S - 1 + BATCH * (b + 1);
      if (E0 <= eMaxProd) {
        const int need = min(E0 + 31, eMaxProd);
        while (__hip_atomic_load(flagProd, __ATOMIC_ACQUIRE, __HIP_MEMORY_SCOPE_AGENT) < need)
          __builtin_amdgcn_s_sleep(2);
        int e = E0 + (lane & 31);
        vbReg = (e <= eMaxProd) ? vbProd[e] : neginf();
      } else vbReg = neginf();
      if (!init) {
        float m = vbReg;
#pragma unroll
        for (int sh = 1; sh < 64; sh <<= 1) m = fmaxf(m, __shfl_xor(m, sh, 64));
        if (m > -1e30f) { oaccF = m; init = true; }
      }
      bu = __builtin_exp2f(fminf(__shfl(vbReg, 0, 64) - oaccF, 120.f));
    }
  }

  if (wg == G - 1 && lane == 63) out[0] = corner * LN2;   // V[N,M]
}

// ---------- fallback (ws too small): proven single-block kernel ----------
constexpr int NTH = 512;
constexpr int RPT = 4;
constexpr int NWAVE = NTH / 64;

__global__ __launch_bounds__(NTH)
void nw_single(const float* __restrict__ th, const float* __restrict__ Aptr,
               float* __restrict__ out)
{
  const int tid  = threadIdx.x;
  const int lane = tid & 63;
  const int wid  = tid >> 6;
  __shared__ float handW[2][NTH];
  __shared__ float wmax[2][NWAVE];
  const float A  = Aptr[0];
  const float eA = __builtin_exp2f(A * LOG2E);
  const int i_base = tid * RPT + 1;
  float W10=0.f,W11=0.f,W12=0.f,W13=0.f,W20=0.f,W21=0.f,W22=0.f,W23=0.f;
  float nb1 = 0.f, nb2 = (tid == 0) ? 1.f : 0.f;
  int oacc = 0;
  const float* thb = th + (size_t)(i_base - 1) * MDP;
  auto loadTh = [&](int d) -> float4 {
    float4 r;
    int c0 = min(max(d - i_base - 1, 0), MDP - 1);
    int c1 = min(max(d - i_base - 2, 0), MDP - 1);
    int c2 = min(max(d - i_base - 3, 0), MDP - 1);
    int c3 = min(max(d - i_base - 4, 0), MDP - 1);
    r.x = thb[c0]; r.y = thb[(size_t)MDP + c1];
    r.z = thb[(size_t)2 * MDP + c2]; r.w = thb[(size_t)3 * MDP + c3];
    return r;
  };
  float4 thA = loadTh(2), thB = loadTh(3);
  for (int d = 2; d <= DTOT; ++d) {
    float4 thC = loadTh(d + 2);
    float n0 = __builtin_exp2f(thA.x*LOG2E)*(eA*(nb1+W10)+nb2);
    float n1 = __builtin_exp2f(thA.y*LOG2E)*(eA*(W10+W11)+W20);
    float n2 = __builtin_exp2f(thA.z*LOG2E)*(eA*(W11+W12)+W21);
    float n3 = __builtin_exp2f(thA.w*LOG2E)*(eA*(W12+W13)+W22);
    W20=W10;W21=W11;W22=W12;W23=W13;
    int cb = d - i_base - 1;
    W10 = ((unsigned)(cb)     < (unsigned)MDP) ? n0 : 0.f;
    W11 = ((unsigned)(cb - 1) < (unsigned)MDP) ? n1 : 0.f;
    W12 = ((unsigned)(cb - 2) < (unsigned)MDP) ? n2 : 0.f;
    W13 = ((unsigned)(cb - 3) < (unsigned)MDP) ? n3 : 0.f;
    const int buf = d & 1;
    const bool rs = ((d & 1) == 0);
    const int wbuf = (d >> 1) & 1;
    if (rs) {
      float m = fmaxf(fmaxf(W10,W11),fmaxf(W12,W13));
#pragma unroll
      for (int sh = 1; sh < 64; sh <<= 1) m = fmaxf(m, __shfl_xor(m, sh, 64));
      if (lane == 0) wmax[wbuf][wid] = m;
    }
    handW[buf][tid] = W13;
    __syncthreads();
    nb2 = nb1;
    nb1 = (tid == 0) ? 0.f : handW[buf][tid - 1];
    if (rs) {
      float bm = wmax[wbuf][0];
#pragma unroll
      for (int w = 1; w < NWAVE; ++w) bm = fmaxf(bm, wmax[wbuf][w]);
      int e = 0;
      if (bm > 0.f) e = (int)((__float_as_uint(bm) >> 23) & 0xFFu) - 126;
      if (e != 0) {
        W10=ldexpf(W10,-e);W11=ldexpf(W11,-e);W12=ldexpf(W12,-e);W13=ldexpf(W13,-e);
        W20=ldexpf(W20,-e);W21=ldexpf(W21,-e);W22=ldexpf(W22,-e);W23=ldexpf(W23,-e);
        nb1=ldexpf(nb1,-e);nb2=ldexpf(nb2,-e);
        oacc += e;
      }
    }
    thA = thB; thB = thC;
  }
  if (tid == NTH - 1) out[0] = logf(W13) + (float)oacc * LN2;
}

extern "C" void kernel_launch(void* const* d_in, const int* in_sizes, int n_in,
                              void* d_out, int out_size, void* d_ws, size_t ws_size,
                              hipStream_t stream)
{
  const float* theta = (const float*)d_in[0];
  const float* A     = (const float*)d_in[1];
  float* out = (float*)d_out;

  const size_t need = (size_t)G * DVB * sizeof(float) + G * 16 * sizeof(int);
  if (ws_size >= need) {
    float* vb  = (float*)d_ws;
    int* flags = (int*)((char*)d_ws + (size_t)G * DVB * sizeof(float));
    hipLaunchKernelGGL(nw_pipe, dim3(G), dim3(64), 0, stream, theta, A, out, vb, flags);
  } else {
    hipLaunchKernelGGL(nw_single, dim3(1), dim3(NTH), 0, stream, theta, A, out);
  }
}